// Round 6
// baseline (8486.531 us; speedup 1.0000x reference)
//
#include <hip/hip_runtime.h>
#include <hip/hip_bf16.h>

// whole_network: attention -> corrcoef -> 5x (GCN + BatchNorm(node) + tanh) -> linear head
// B=8192, N=100 (pad 112), T=64. MFMA bf16 16x16x32; hi/lo double-bf16 on all
// precision-critical operands (x,W,A,chat,corr-in-LDS,t0,t) => ~f32 accuracy.

typedef unsigned int u32;
typedef unsigned short u16;
typedef float f32x4 __attribute__((ext_vector_type(4)));
typedef short s16x8 __attribute__((ext_vector_type(8)));

__device__ __forceinline__ f32x4 mfma16(s16x8 a, s16x8 b, f32x4 c) {
  return __builtin_amdgcn_mfma_f32_16x16x32_bf16(a, b, c, 0, 0, 0);
}
__device__ __forceinline__ u16 f2b(float f) {
  __hip_bfloat16 h = __float2bfloat16(f);
  u16 u; __builtin_memcpy(&u, &h, 2); return u;
}
__device__ __forceinline__ float b2f(u16 u) { return __uint_as_float((u32)u << 16); }
__device__ __forceinline__ u32 pack_hi2(float a, float b) { return (u32)f2b(a) | ((u32)f2b(b) << 16); }
__device__ __forceinline__ u32 pack_lo2(float a, float b) {
  return (u32)f2b(a - b2f(f2b(a))) | ((u32)f2b(b - b2f(f2b(b))) << 16);
}
__device__ __forceinline__ float fast_tanh(float x) {
  float e = __expf(2.0f * x);
  return 1.0f - 2.0f * __builtin_amdgcn_rcpf(e + 1.0f);
}

// ---------------- KA LDS map (u16 indices; byte = 2*idx), total 113152 B ----------------
// P0-P1: x_hi[112][72]@0, x_lo@8064, W_hi[128][72]@16128, W_lo@25344 (ends 34560)
// P2-P3: A_hi[112][136]@0, A_lo@15232 (over x/W)
// P4-P5: corr_hi[112][136]@0, corr_lo@15232 (over A)
// Q/chat_hi[112][40]@34560 ; K/chat_lo@39040
// Vt[32][136]@43520 ; t0_hi[32][136]@47872 ; t0_lo@52224 (ends 56576)
#define KA_XHI   0
#define KA_XLO   8064
#define KA_WHI   16128
#define KA_WLO   25344
#define KA_AHI   0
#define KA_ALO   15232
#define KA_CHI   0
#define KA_CLO   15232
#define KA_Q     34560
#define KA_K     39040
#define KA_VT    43520
#define KA_T0H   47872
#define KA_T0L   52224
#define KA_SX    72
#define KA_ASX   136
#define KA_QSX   40
#define KA_SMEM  113152

__global__ __launch_bounds__(512, 2) void ka_kernel(
    const float* __restrict__ x,
    const float* __restrict__ Wq, const float* __restrict__ bq,
    const float* __restrict__ Wk, const float* __restrict__ bk,
    const float* __restrict__ Wv, const float* __restrict__ bv,
    const float* __restrict__ W1, const float* __restrict__ b1,
    __hip_bfloat16* __restrict__ corr_g,   // [B,100,100] bf16
    float* __restrict__ z1g,               // [B,100,32] f32
    float* __restrict__ stats1)            // [200]
{
  __shared__ __align__(16) char smem[KA_SMEM];
  u16* S16 = (u16*)smem;
  const int b = blockIdx.x, tid = threadIdx.x;
  const int w = tid >> 6, l = tid & 63, l15 = l & 15, g = l >> 4;
  const f32x4 zero4 = {0.f, 0.f, 0.f, 0.f};

  // ---- P0: stage x hi/lo (rows>=100 zero), Wcat=[Wq;Wk;Wv;W1] hi/lo; zero Vt/t0 pad cols
  {
    const float2* xg2 = (const float2*)(x + (size_t)b * 6400);
    for (int i = tid; i < 112 * 32; i += 512) {
      int r = i >> 5, c2 = i & 31;
      float vx = 0.f, vy = 0.f;
      if (r < 100) { float2 v = xg2[r * 32 + c2]; vx = v.x; vy = v.y; }
      *(u32*)&S16[KA_XHI + r * KA_SX + c2 * 2] = pack_hi2(vx, vy);
      *(u32*)&S16[KA_XLO + r * KA_SX + c2 * 2] = pack_lo2(vx, vy);
    }
    for (int i = tid; i < 128 * 32; i += 512) {
      int r = i >> 5, c2 = i & 31;
      const float* Wp = (r < 32) ? Wq : (r < 64) ? Wk : (r < 96) ? Wv : W1;
      float2 v = ((const float2*)Wp)[(r & 31) * 32 + c2];
      *(u32*)&S16[KA_WHI + r * KA_SX + c2 * 2] = pack_hi2(v.x, v.y);
      *(u32*)&S16[KA_WLO + r * KA_SX + c2 * 2] = pack_lo2(v.x, v.y);
    }
    for (int i = tid; i < 1152; i += 512) {          // Vt/t0_hi/t0_lo cols 112..135 := 0
      int arr = i / 384, rem = i - arr * 384;
      int r = rem / 12, c = rem - r * 12;
      int base = (arr == 0) ? KA_VT : (arr == 1) ? KA_T0H : KA_T0L;
      *(u32*)&S16[base + r * KA_ASX + 112 + c * 2] = 0;
    }
  }
  __syncthreads();

  // ---- P1: [Q|K|V|t0] = x @ Wcat^T, 3-term hi/lo MFMA (exact); wave w owns 16-col slab w
  {
    const int mi = w >> 1;                  // 0:Q 1:K 2:V 3:t0
    const int j = 16 * (w & 1) + l15;       // 0..31 within matrix
    float bias = 0.f;
    if (mi == 0) bias = bq[j]; else if (mi == 1) bias = bk[j]; else if (mi == 2) bias = bv[j];
    for (int tm = 0; tm < 7; ++tm) {
      f32x4 acc = zero4;
#pragma unroll
      for (int kt = 0; kt < 2; ++kt) {
        s16x8 ah = *(const s16x8*)&S16[KA_XHI + (16 * tm + l15) * KA_SX + g * 8 + kt * 32];
        s16x8 al = *(const s16x8*)&S16[KA_XLO + (16 * tm + l15) * KA_SX + g * 8 + kt * 32];
        s16x8 bh = *(const s16x8*)&S16[KA_WHI + (16 * w + l15) * KA_SX + g * 8 + kt * 32];
        s16x8 bl = *(const s16x8*)&S16[KA_WLO + (16 * w + l15) * KA_SX + g * 8 + kt * 32];
        acc = mfma16(al, bh, acc);
        acc = mfma16(ah, bl, acc);
        acc = mfma16(ah, bh, acc);
      }
      const int row0 = 16 * tm + 4 * g;
#pragma unroll
      for (int r = 0; r < 4; ++r) {
        int row = row0 + r;
        float v = acc[r] + bias;
        u16 hv = f2b(v);
        if (mi == 0)      S16[KA_Q  + row * KA_QSX + j] = hv;
        else if (mi == 1) S16[KA_K  + row * KA_QSX + j] = hv;
        else if (mi == 2) S16[KA_VT + j * KA_ASX + row] = hv;    // transposed
        else {                                                    // t0 hi/lo, transposed
          S16[KA_T0H + j * KA_ASX + row] = hv;
          S16[KA_T0L + j * KA_ASX + row] = f2b(v - b2f(hv));
        }
      }
    }
  }
  __syncthreads();

  // ---- P2: S = Q K^T (MFMA), softmax rows, write A hi/lo [112][136] over x/W region
  {
    for (int i = tid; i < 2688; i += 512) {          // A_hi/A_lo cols 112..135 := 0
      int arr = i / 1344, rem = i - arr * 1344;
      int r = rem / 12, c = rem - r * 12;
      *(u32*)&S16[(arr ? KA_ALO : KA_AHI) + r * KA_ASX + 112 + c * 2] = 0;
    }
    if (w < 7) {
      const int tm = w;
      s16x8 aq = *(const s16x8*)&S16[KA_Q + (16 * tm + l15) * KA_QSX + g * 8];
      f32x4 sc[7];
#pragma unroll
      for (int tn = 0; tn < 7; ++tn) {
        s16x8 bb = *(const s16x8*)&S16[KA_K + (16 * tn + l15) * KA_QSX + g * 8];
        sc[tn] = mfma16(aq, bb, zero4);
      }
      const int row0 = 16 * tm + 4 * g;
#pragma unroll
      for (int r = 0; r < 4; ++r) {
        const int row = row0 + r;
        float v[7];
#pragma unroll
        for (int tn = 0; tn < 7; ++tn) v[tn] = sc[tn][r];
        if (l15 >= 4) v[6] = -3.0e38f;               // mask cols >= 100
        float m = v[0];
#pragma unroll
        for (int tn = 1; tn < 7; ++tn) m = fmaxf(m, v[tn]);
#pragma unroll
        for (int off = 1; off < 16; off <<= 1) m = fmaxf(m, __shfl_xor(m, off, 16));
        float e[7], s = 0.f;
#pragma unroll
        for (int tn = 0; tn < 7; ++tn) { e[tn] = __expf((v[tn] - m) * 0.03125f); s += e[tn]; }
#pragma unroll
        for (int off = 1; off < 16; off <<= 1) s += __shfl_xor(s, off, 16);
        float rr = __builtin_amdgcn_rcpf(s);
        bool ok = row < 100;
#pragma unroll
        for (int tn = 0; tn < 7; ++tn) {
          float a = ok ? e[tn] * rr : 0.f;
          u16 ah = f2b(a);
          S16[KA_AHI + row * KA_ASX + 16 * tn + l15] = ah;
          S16[KA_ALO + row * KA_ASX + 16 * tn + l15] = f2b(a - b2f(ah));
        }
      }
    }
  }
  __syncthreads();

  // ---- P3: feat = (A_hi+A_lo) @ V (MFMA); row-normalize -> chat hi (Q) + lo (K)
  if (w < 7) {
    const int tm = w;
    f32x4 f0 = zero4, f1 = zero4;
#pragma unroll
    for (int kt = 0; kt < 4; ++kt) {
      s16x8 ah  = *(const s16x8*)&S16[KA_AHI + (16 * tm + l15) * KA_ASX + g * 8 + kt * 32];
      s16x8 al  = *(const s16x8*)&S16[KA_ALO + (16 * tm + l15) * KA_ASX + g * 8 + kt * 32];
      s16x8 b0  = *(const s16x8*)&S16[KA_VT + l15 * KA_ASX + g * 8 + kt * 32];
      s16x8 b1v = *(const s16x8*)&S16[KA_VT + (16 + l15) * KA_ASX + g * 8 + kt * 32];
      f0 = mfma16(al, b0, f0);  f0 = mfma16(ah, b0, f0);
      f1 = mfma16(al, b1v, f1); f1 = mfma16(ah, b1v, f1);
    }
    const int row0 = 16 * tm + 4 * g;
#pragma unroll
    for (int r = 0; r < 4; ++r) {
      float v0 = f0[r], v1 = f1[r];
      float s = v0 + v1;
#pragma unroll
      for (int off = 1; off < 16; off <<= 1) s += __shfl_xor(s, off, 16);
      float mean = s * 0.03125f;
      float xc0 = v0 - mean, xc1 = v1 - mean;
      float q = xc0 * xc0 + xc1 * xc1;
#pragma unroll
      for (int off = 1; off < 16; off <<= 1) q += __shfl_xor(q, off, 16);
      float inv = rsqrtf(q + 1e-30f);                // zero rows stay exactly 0
      const int row = row0 + r;
      float c0 = xc0 * inv, c1 = xc1 * inv;
      u16 h0 = f2b(c0), h1 = f2b(c1);
      S16[KA_Q + row * KA_QSX + l15]      = h0;
      S16[KA_Q + row * KA_QSX + 16 + l15] = h1;
      S16[KA_K + row * KA_QSX + l15]      = f2b(c0 - b2f(h0));
      S16[KA_K + row * KA_QSX + 16 + l15] = f2b(c1 - b2f(h1));
    }
  }
  __syncthreads();

  // ---- P4: corr = clip(3-term chat@chat^T) -> corr hi/lo LDS (over A) + HBM bf16
  if (w < 7) {
    u16* cgu = (u16*)(corr_g + (size_t)b * 10000);
    const int tm = w;
    s16x8 ah = *(const s16x8*)&S16[KA_Q + (16 * tm + l15) * KA_QSX + g * 8];
    s16x8 al = *(const s16x8*)&S16[KA_K + (16 * tm + l15) * KA_QSX + g * 8];
    const int row0 = 16 * tm + 4 * g;
#pragma unroll
    for (int tn = 0; tn < 7; ++tn) {
      s16x8 bh = *(const s16x8*)&S16[KA_Q + (16 * tn + l15) * KA_QSX + g * 8];
      s16x8 bl = *(const s16x8*)&S16[KA_K + (16 * tn + l15) * KA_QSX + g * 8];
      f32x4 c = mfma16(al, bh, zero4);
      c = mfma16(ah, bl, c);
      c = mfma16(ah, bh, c);
      const int col = 16 * tn + l15;
#pragma unroll
      for (int r = 0; r < 4; ++r) {
        float d = fminf(1.f, fmaxf(-1.f, c[r]));
        u16 ch = f2b(d);
        const int row = row0 + r;
        S16[KA_CHI + row * KA_ASX + col] = ch;
        S16[KA_CLO + row * KA_ASX + col] = f2b(d - b2f(ch));
        if (row < 100 && col < 100) cgu[row * 100 + col] = ch;
      }
    }
  }
  __syncthreads();

  // ---- P5: z1 = (corr_hi+corr_lo) @ (t0_hi+t0_lo) + b1 -> HBM f32 + stats
  if (w < 7) {
    const int tm = w;
    float bj0 = b1[l15], bj1 = b1[16 + l15];
    float* zo = z1g + (size_t)b * 3200;
    f32x4 z0 = zero4, z1v = zero4;
#pragma unroll
    for (int kt = 0; kt < 4; ++kt) {
      s16x8 a_h = *(const s16x8*)&S16[KA_CHI + (16 * tm + l15) * KA_ASX + g * 8 + kt * 32];
      s16x8 a_l = *(const s16x8*)&S16[KA_CLO + (16 * tm + l15) * KA_ASX + g * 8 + kt * 32];
      s16x8 b0h = *(const s16x8*)&S16[KA_T0H + l15 * KA_ASX + g * 8 + kt * 32];
      s16x8 b0l = *(const s16x8*)&S16[KA_T0L + l15 * KA_ASX + g * 8 + kt * 32];
      s16x8 b1h = *(const s16x8*)&S16[KA_T0H + (16 + l15) * KA_ASX + g * 8 + kt * 32];
      s16x8 b1l = *(const s16x8*)&S16[KA_T0L + (16 + l15) * KA_ASX + g * 8 + kt * 32];
      z0 = mfma16(a_l, b0h, z0);  z0 = mfma16(a_h, b0l, z0);  z0 = mfma16(a_h, b0h, z0);
      z1v = mfma16(a_l, b1h, z1v); z1v = mfma16(a_h, b1l, z1v); z1v = mfma16(a_h, b1h, z1v);
    }
    const int row0 = 16 * tm + 4 * g;
#pragma unroll
    for (int r = 0; r < 4; ++r) {
      const int row = row0 + r;
      float v0 = z0[r] + bj0, v1 = z1v[r] + bj1;
      if (row < 100) { zo[row * 32 + l15] = v0; zo[row * 32 + 16 + l15] = v1; }
      float s = v0 + v1, ss = v0 * v0 + v1 * v1;
#pragma unroll
      for (int off = 1; off < 16; off <<= 1) {
        s += __shfl_xor(s, off, 16); ss += __shfl_xor(ss, off, 16);
      }
      if (row < 100 && l15 == 0) { atomicAdd(&stats1[row], s); atomicAdd(&stats1[100 + row], ss); }
    }
  }
}

// ---------------- KB: h = tanh(BN(z)); t = h@W^T (hi/lo); z' = corr@(t_hi+t_lo)+b ----------------
// LDS: corrL [112][136] u16 @0 ; hL f32[100][33] @30464B ; tt_hi [16][136] @43664B ;
//      tt_lo [16][136] @48016B ; mS/vS @52368B
#define KB_HL   30464
#define KB_TT   43664
#define KB_TTL  48016
#define KB_MS   52368
#define KB_SMEM 53168    // 3 blocks/CU

template<int FIN, int FOUT>
__global__ __launch_bounds__(256, 3) void kb_kernel(
    const float* __restrict__ zin,
    const __hip_bfloat16* __restrict__ corr_g,
    const float* __restrict__ W, const float* __restrict__ bias,
    const float* __restrict__ stats_in, float* __restrict__ stats_out,
    float* __restrict__ zout)
{
  constexpr int LOGF  = (FOUT == 16) ? 4 : (FOUT == 8) ? 3 : (FOUT == 4) ? 2 : 1;
  constexpr int LOGFI = (FIN == 32) ? 5 : (FIN == 16) ? 4 : (FIN == 8) ? 3 : 2;
  constexpr int RP = 256 / FOUT;
  constexpr int NR = (100 + RP - 1) / RP;

  __shared__ __align__(16) char smem[KB_SMEM];
  u16* S16 = (u16*)smem;
  float* hL = (float*)(smem + KB_HL);
  u16* tt  = (u16*)(smem + KB_TT);
  u16* ttl = (u16*)(smem + KB_TTL);
  float* mS = (float*)(smem + KB_MS);
  float* vS = mS + 100;

  const int b = blockIdx.x, tid = threadIdx.x;
  const f32x4 zero4 = {0.f, 0.f, 0.f, 0.f};

  // PH0: stage corr (bf16 u32 copy) + zero pads; tt/ttl := 0; BN stats -> mS/vS
  {
    const u32* cgu = (const u32*)(corr_g + (size_t)b * 10000);
    u32* cl = (u32*)smem;                     // [112][68] u32 view
    for (int i = tid; i < 5000; i += 256) {
      int n = (i * 5243) >> 18;               // i/50
      int mm = i - n * 50;
      cl[n * 68 + mm] = cgu[i];
    }
    for (int i = tid; i < 1800; i += 256) {   // rows<100, u32 cols 50..67 := 0
      int n = i / 18, c = i - n * 18;
      cl[n * 68 + 50 + c] = 0;
    }
    for (int i = tid; i < 816; i += 256) {    // rows 100..111 := 0
      int n = i / 68, c = i - n * 68;
      cl[(100 + n) * 68 + c] = 0;
    }
    u32* ttz = (u32*)tt;                      // tt + ttl contiguous: 8704 B
    for (int i = tid; i < 2176; i += 256) ttz[i] = 0;
    if (tid < 100) {
      float cnt  = 8192.0f * (float)FIN;
      float mean = stats_in[tid] / cnt;
      float var  = stats_in[100 + tid] / cnt - mean * mean;
      mS[tid] = mean; vS[tid] = rsqrtf(var + 1e-5f);
    }
  }
  __syncthreads();

  // PH1: h = tanh(BN(z)) -> hL
  {
    const float4* zb4 = (const float4*)(zin + (size_t)b * 100 * FIN);
    for (int i4 = tid; i4 < 25 * FIN; i4 += 256) {
      int n = i4 >> (LOGFI - 2);
      int c = (i4 << 2) & (FIN - 1);
      float4 z = zb4[i4];
      float mn = mS[n], iv = vS[n];
      hL[n * 33 + c + 0] = fast_tanh((z.x - mn) * iv);
      hL[n * 33 + c + 1] = fast_tanh((z.y - mn) * iv);
      hL[n * 33 + c + 2] = fast_tanh((z.z - mn) * iv);
      hL[n * 33 + c + 3] = fast_tanh((z.w - mn) * iv);
    }
  }
  __syncthreads();

  // PH2: t = h @ W^T -> tt/ttl [j][n] bf16 hi/lo (transposed)
  {
    const int j = tid & (FOUT - 1);
    const int nbk = tid >> LOGF;
    float wreg[FIN];
#pragma unroll
    for (int c = 0; c < FIN; ++c) wreg[c] = W[j * FIN + c];
#pragma unroll
    for (int k = 0; k < NR; ++k) {
      int n = nbk + k * RP;
      if (n < 100) {
        float a = 0.f;
#pragma unroll
        for (int c = 0; c < FIN; ++c) a = fmaf(hL[n * 33 + c], wreg[c], a);
        u16 hh = f2b(a);
        tt[j * 136 + n]  = hh;
        ttl[j * 136 + n] = f2b(a - b2f(hh));
      }
    }
  }
  __syncthreads();

  // PH3: z' = corr @ (t_hi + t_lo) + bias (MFMA) ; stats
  {
    const int w = tid >> 6, l15 = tid & 15, g = (tid & 63) >> 4;
    const int nb = (w < 3) ? 2 : 1;
    float bj = (l15 < FOUT) ? bias[l15] : 0.f;
    float* zo = zout + (size_t)b * 100 * FOUT;
    for (int bi = 0; bi < nb; ++bi) {
      const int tm = w + 4 * bi;
      f32x4 acc = zero4;
#pragma unroll
      for (int kt = 0; kt < 4; ++kt) {
        s16x8 a  = *(const s16x8*)&S16[(16 * tm + l15) * 136 + g * 8 + kt * 32];
        s16x8 bh = *(const s16x8*)&tt[l15 * 136 + g * 8 + kt * 32];
        s16x8 bl = *(const s16x8*)&ttl[l15 * 136 + g * 8 + kt * 32];
        acc = mfma16(a, bl, acc);
        acc = mfma16(a, bh, acc);
      }
      const int row0 = 16 * tm + 4 * g;
      const bool jok = l15 < FOUT;
#pragma unroll
      for (int r = 0; r < 4; ++r) {
        const int row = row0 + r;
        float v = acc[r] + bj;
        if (row < 100 && jok) zo[row * FOUT + l15] = v;
        float s = jok ? v : 0.f, ss = jok ? v * v : 0.f;
#pragma unroll
        for (int off = 1; off < 16; off <<= 1) {
          s += __shfl_xor(s, off, 16); ss += __shfl_xor(ss, off, 16);
        }
        if (row < 100 && l15 == 0) { atomicAdd(&stats_out[row], s); atomicAdd(&stats_out[100 + row], ss); }
      }
    }
  }
}

// ---------------- KF: final BN+tanh + [200]->[2] head ----------------
__global__ __launch_bounds__(256) void kf_kernel(
    const float* __restrict__ z5, const float* __restrict__ stats5,
    const float* __restrict__ Wf, const float* __restrict__ bfv,
    float* __restrict__ out)
{
  __shared__ float mS[100], vS[100];
  const int tid = threadIdx.x;
  if (tid < 100) {
    float cnt  = 8192.0f * 2.0f;
    float mean = stats5[tid] / cnt;
    float var  = stats5[100 + tid] / cnt - mean * mean;
    mS[tid] = mean;
    vS[tid] = rsqrtf(var + 1e-5f);
  }
  __syncthreads();
  const int wvid = tid >> 6, lane = tid & 63;
  const int b = blockIdx.x * 4 + wvid;
  const float* zb = z5 + (size_t)b * 200;
  float a0 = 0.f, a1 = 0.f;
#pragma unroll
  for (int p = 0; p < 4; ++p) {
    int jj = lane + p * 64;
    if (jj < 200) {
      int n = jj >> 1;
      float hv = fast_tanh((zb[jj] - mS[n]) * vS[n]);
      a0 = fmaf(hv, Wf[jj], a0);
      a1 = fmaf(hv, Wf[200 + jj], a1);
    }
  }
#pragma unroll
  for (int off = 32; off; off >>= 1) {
    a0 += __shfl_xor(a0, off, 64);
    a1 += __shfl_xor(a1, off, 64);
  }
  if (lane == 0) {
    out[b * 2 + 0] = a0 + bfv[0];
    out[b * 2 + 1] = a1 + bfv[1];
  }
}

extern "C" void kernel_launch(void* const* d_in, const int* in_sizes, int n_in,
                              void* d_out, int out_size, void* d_ws, size_t ws_size,
                              hipStream_t stream)
{
  const float* x  = (const float*)d_in[0];
  const float* Wq = (const float*)d_in[1];
  const float* bq = (const float*)d_in[2];
  const float* Wk = (const float*)d_in[3];
  const float* bk = (const float*)d_in[4];
  const float* Wv = (const float*)d_in[5];
  const float* bv = (const float*)d_in[6];
  const float* W1 = (const float*)d_in[7];
  const float* b1 = (const float*)d_in[8];
  const float* W2 = (const float*)d_in[9];
  const float* b2 = (const float*)d_in[10];
  const float* W3 = (const float*)d_in[11];
  const float* b3 = (const float*)d_in[12];
  const float* W4 = (const float*)d_in[13];
  const float* b4 = (const float*)d_in[14];
  const float* W5 = (const float*)d_in[15];
  const float* b5 = (const float*)d_in[16];
  const float* Wf = (const float*)d_in[17];
  const float* bf = (const float*)d_in[18];
  float* out = (float*)d_out;

  char* ws = (char*)d_ws;
  // ws: corr bf16 [8192,100,100] @0 ; zA f32 [8192,100,32] @163840000 ;
  //     zB f32 [8192,100,16] @268697600 ; stats 5*[200] f32 @321126400
  const size_t NEED = 321130400ull;
  if (ws_size < NEED) return;

  __hip_bfloat16* corr_g = (__hip_bfloat16*)ws;
  float* zA    = (float*)(ws + 163840000ull);
  float* zB    = (float*)(ws + 268697600ull);
  float* stats = (float*)(ws + 321126400ull);

  (void)hipMemsetAsync(stats, 0, 5 * 200 * sizeof(float), stream);

  ka_kernel<<<8192, 512, 0, stream>>>(x, Wq, bq, Wk, bk, Wv, bv, W1, b1,
                                      corr_g, zA, stats);
  kb_kernel<32, 16><<<8192, 256, 0, stream>>>(zA, corr_g, W2, b2, stats,       stats + 200, zB);
  kb_kernel<16,  8><<<8192, 256, 0, stream>>>(zB, corr_g, W3, b3, stats + 200, stats + 400, zA);
  kb_kernel< 8,  4><<<8192, 256, 0, stream>>>(zA, corr_g, W4, b4, stats + 400, stats + 600, zB);
  kb_kernel< 4,  2><<<8192, 256, 0, stream>>>(zB, corr_g, W5, b5, stats + 600, stats + 800, zA);
  kf_kernel<<<2048, 256, 0, stream>>>(zA, stats + 800, Wf, bf, out);
}

// Round 7
// 4018.671 us; speedup vs baseline: 2.1118x; 2.1118x over previous
//
#include <hip/hip_runtime.h>
#include <hip/hip_bf16.h>

// whole_network: attention -> corrcoef -> 5x (GCN + BatchNorm(node) + tanh) -> linear head
// B=8192, N=100, T=64.
// KA: MFMA bf16 16x16x32 with hi/lo double-bf16 (R6, proven absmax 0.0039, ~1.3ms).
// KB/KF: R2-proven VALU structure (550us/layer measured) -- bisecting R6's KB regression.

typedef unsigned int u32;
typedef unsigned short u16;
typedef float f32x4 __attribute__((ext_vector_type(4)));
typedef short s16x8 __attribute__((ext_vector_type(8)));

__device__ __forceinline__ f32x4 mfma16(s16x8 a, s16x8 b, f32x4 c) {
  return __builtin_amdgcn_mfma_f32_16x16x32_bf16(a, b, c, 0, 0, 0);
}
__device__ __forceinline__ u16 f2b(float f) {
  __hip_bfloat16 h = __float2bfloat16(f);
  u16 u; __builtin_memcpy(&u, &h, 2); return u;
}
__device__ __forceinline__ float b2f(u16 u) { return __uint_as_float((u32)u << 16); }
__device__ __forceinline__ float blo(u32 u) { return __uint_as_float(u << 16); }
__device__ __forceinline__ float bhi(u32 u) { return __uint_as_float(u & 0xffff0000u); }
__device__ __forceinline__ u32 pack_hi2(float a, float b) { return (u32)f2b(a) | ((u32)f2b(b) << 16); }
__device__ __forceinline__ u32 pack_lo2(float a, float b) {
  return (u32)f2b(a - b2f(f2b(a))) | ((u32)f2b(b - b2f(f2b(b))) << 16);
}
__device__ __forceinline__ float fast_tanh(float x) {
  float e = __expf(2.0f * x);
  return 1.0f - 2.0f * __builtin_amdgcn_rcpf(e + 1.0f);
}

// ---------------- KA LDS map (u16 indices; byte = 2*idx), total 113152 B ----------------
#define KA_XHI   0
#define KA_XLO   8064
#define KA_WHI   16128
#define KA_WLO   25344
#define KA_AHI   0
#define KA_ALO   15232
#define KA_CHI   0
#define KA_CLO   15232
#define KA_Q     34560
#define KA_K     39040
#define KA_VT    43520
#define KA_T0H   47872
#define KA_T0L   52224
#define KA_SX    72
#define KA_ASX   136
#define KA_QSX   40
#define KA_SMEM  113152

__global__ __launch_bounds__(512, 2) void ka_kernel(
    const float* __restrict__ x,
    const float* __restrict__ Wq, const float* __restrict__ bq,
    const float* __restrict__ Wk, const float* __restrict__ bk,
    const float* __restrict__ Wv, const float* __restrict__ bv,
    const float* __restrict__ W1, const float* __restrict__ b1,
    __hip_bfloat16* __restrict__ corr_g,   // [B,100,100] bf16
    float* __restrict__ z1g,               // [B,100,32] f32
    float* __restrict__ stats1)            // [200]
{
  __shared__ __align__(16) char smem[KA_SMEM];
  u16* S16 = (u16*)smem;
  const int b = blockIdx.x, tid = threadIdx.x;
  const int w = tid >> 6, l = tid & 63, l15 = l & 15, g = l >> 4;
  const f32x4 zero4 = {0.f, 0.f, 0.f, 0.f};

  // ---- P0: stage x hi/lo (rows>=100 zero), Wcat=[Wq;Wk;Wv;W1] hi/lo; zero Vt/t0 pad cols
  {
    const float2* xg2 = (const float2*)(x + (size_t)b * 6400);
    for (int i = tid; i < 112 * 32; i += 512) {
      int r = i >> 5, c2 = i & 31;
      float vx = 0.f, vy = 0.f;
      if (r < 100) { float2 v = xg2[r * 32 + c2]; vx = v.x; vy = v.y; }
      *(u32*)&S16[KA_XHI + r * KA_SX + c2 * 2] = pack_hi2(vx, vy);
      *(u32*)&S16[KA_XLO + r * KA_SX + c2 * 2] = pack_lo2(vx, vy);
    }
    for (int i = tid; i < 128 * 32; i += 512) {
      int r = i >> 5, c2 = i & 31;
      const float* Wp = (r < 32) ? Wq : (r < 64) ? Wk : (r < 96) ? Wv : W1;
      float2 v = ((const float2*)Wp)[(r & 31) * 32 + c2];
      *(u32*)&S16[KA_WHI + r * KA_SX + c2 * 2] = pack_hi2(v.x, v.y);
      *(u32*)&S16[KA_WLO + r * KA_SX + c2 * 2] = pack_lo2(v.x, v.y);
    }
    for (int i = tid; i < 1152; i += 512) {          // Vt/t0_hi/t0_lo cols 112..135 := 0
      int arr = i / 384, rem = i - arr * 384;
      int r = rem / 12, c = rem - r * 12;
      int base = (arr == 0) ? KA_VT : (arr == 1) ? KA_T0H : KA_T0L;
      *(u32*)&S16[base + r * KA_ASX + 112 + c * 2] = 0;
    }
  }
  __syncthreads();

  // ---- P1: [Q|K|V|t0] = x @ Wcat^T, 3-term hi/lo MFMA (exact); wave w owns 16-col slab w
  {
    const int mi = w >> 1;                  // 0:Q 1:K 2:V 3:t0
    const int j = 16 * (w & 1) + l15;       // 0..31 within matrix
    float bias = 0.f;
    if (mi == 0) bias = bq[j]; else if (mi == 1) bias = bk[j]; else if (mi == 2) bias = bv[j];
    for (int tm = 0; tm < 7; ++tm) {
      f32x4 acc = zero4;
#pragma unroll
      for (int kt = 0; kt < 2; ++kt) {
        s16x8 ah = *(const s16x8*)&S16[KA_XHI + (16 * tm + l15) * KA_SX + g * 8 + kt * 32];
        s16x8 al = *(const s16x8*)&S16[KA_XLO + (16 * tm + l15) * KA_SX + g * 8 + kt * 32];
        s16x8 bh = *(const s16x8*)&S16[KA_WHI + (16 * w + l15) * KA_SX + g * 8 + kt * 32];
        s16x8 bl = *(const s16x8*)&S16[KA_WLO + (16 * w + l15) * KA_SX + g * 8 + kt * 32];
        acc = mfma16(al, bh, acc);
        acc = mfma16(ah, bl, acc);
        acc = mfma16(ah, bh, acc);
      }
      const int row0 = 16 * tm + 4 * g;
#pragma unroll
      for (int r = 0; r < 4; ++r) {
        int row = row0 + r;
        float v = acc[r] + bias;
        u16 hv = f2b(v);
        if (mi == 0)      S16[KA_Q  + row * KA_QSX + j] = hv;
        else if (mi == 1) S16[KA_K  + row * KA_QSX + j] = hv;
        else if (mi == 2) S16[KA_VT + j * KA_ASX + row] = hv;    // transposed
        else {                                                    // t0 hi/lo, transposed
          S16[KA_T0H + j * KA_ASX + row] = hv;
          S16[KA_T0L + j * KA_ASX + row] = f2b(v - b2f(hv));
        }
      }
    }
  }
  __syncthreads();

  // ---- P2: S = Q K^T (MFMA), softmax rows, write A hi/lo [112][136] over x/W region
  {
    for (int i = tid; i < 2688; i += 512) {          // A_hi/A_lo cols 112..135 := 0
      int arr = i / 1344, rem = i - arr * 1344;
      int r = rem / 12, c = rem - r * 12;
      *(u32*)&S16[(arr ? KA_ALO : KA_AHI) + r * KA_ASX + 112 + c * 2] = 0;
    }
    if (w < 7) {
      const int tm = w;
      s16x8 aq = *(const s16x8*)&S16[KA_Q + (16 * tm + l15) * KA_QSX + g * 8];
      f32x4 sc[7];
#pragma unroll
      for (int tn = 0; tn < 7; ++tn) {
        s16x8 bb = *(const s16x8*)&S16[KA_K + (16 * tn + l15) * KA_QSX + g * 8];
        sc[tn] = mfma16(aq, bb, zero4);
      }
      const int row0 = 16 * tm + 4 * g;
#pragma unroll
      for (int r = 0; r < 4; ++r) {
        const int row = row0 + r;
        float v[7];
#pragma unroll
        for (int tn = 0; tn < 7; ++tn) v[tn] = sc[tn][r];
        if (l15 >= 4) v[6] = -3.0e38f;               // mask cols >= 100
        float m = v[0];
#pragma unroll
        for (int tn = 1; tn < 7; ++tn) m = fmaxf(m, v[tn]);
#pragma unroll
        for (int off = 1; off < 16; off <<= 1) m = fmaxf(m, __shfl_xor(m, off, 16));
        float e[7], s = 0.f;
#pragma unroll
        for (int tn = 0; tn < 7; ++tn) { e[tn] = __expf((v[tn] - m) * 0.03125f); s += e[tn]; }
#pragma unroll
        for (int off = 1; off < 16; off <<= 1) s += __shfl_xor(s, off, 16);
        float rr = __builtin_amdgcn_rcpf(s);
        bool ok = row < 100;
#pragma unroll
        for (int tn = 0; tn < 7; ++tn) {
          float a = ok ? e[tn] * rr : 0.f;
          u16 ah = f2b(a);
          S16[KA_AHI + row * KA_ASX + 16 * tn + l15] = ah;
          S16[KA_ALO + row * KA_ASX + 16 * tn + l15] = f2b(a - b2f(ah));
        }
      }
    }
  }
  __syncthreads();

  // ---- P3: feat = (A_hi+A_lo) @ V (MFMA); row-normalize -> chat hi (Q) + lo (K)
  if (w < 7) {
    const int tm = w;
    f32x4 f0 = zero4, f1 = zero4;
#pragma unroll
    for (int kt = 0; kt < 4; ++kt) {
      s16x8 ah  = *(const s16x8*)&S16[KA_AHI + (16 * tm + l15) * KA_ASX + g * 8 + kt * 32];
      s16x8 al  = *(const s16x8*)&S16[KA_ALO + (16 * tm + l15) * KA_ASX + g * 8 + kt * 32];
      s16x8 b0  = *(const s16x8*)&S16[KA_VT + l15 * KA_ASX + g * 8 + kt * 32];
      s16x8 b1v = *(const s16x8*)&S16[KA_VT + (16 + l15) * KA_ASX + g * 8 + kt * 32];
      f0 = mfma16(al, b0, f0);  f0 = mfma16(ah, b0, f0);
      f1 = mfma16(al, b1v, f1); f1 = mfma16(ah, b1v, f1);
    }
    const int row0 = 16 * tm + 4 * g;
#pragma unroll
    for (int r = 0; r < 4; ++r) {
      float v0 = f0[r], v1 = f1[r];
      float s = v0 + v1;
#pragma unroll
      for (int off = 1; off < 16; off <<= 1) s += __shfl_xor(s, off, 16);
      float mean = s * 0.03125f;
      float xc0 = v0 - mean, xc1 = v1 - mean;
      float q = xc0 * xc0 + xc1 * xc1;
#pragma unroll
      for (int off = 1; off < 16; off <<= 1) q += __shfl_xor(q, off, 16);
      float inv = rsqrtf(q + 1e-30f);                // zero rows stay exactly 0
      const int row = row0 + r;
      float c0 = xc0 * inv, c1 = xc1 * inv;
      u16 h0 = f2b(c0), h1 = f2b(c1);
      S16[KA_Q + row * KA_QSX + l15]      = h0;
      S16[KA_Q + row * KA_QSX + 16 + l15] = h1;
      S16[KA_K + row * KA_QSX + l15]      = f2b(c0 - b2f(h0));
      S16[KA_K + row * KA_QSX + 16 + l15] = f2b(c1 - b2f(h1));
    }
  }
  __syncthreads();

  // ---- P4: corr = clip(3-term chat@chat^T) -> corr hi/lo LDS (over A) + HBM bf16
  if (w < 7) {
    u16* cgu = (u16*)(corr_g + (size_t)b * 10000);
    const int tm = w;
    s16x8 ah = *(const s16x8*)&S16[KA_Q + (16 * tm + l15) * KA_QSX + g * 8];
    s16x8 al = *(const s16x8*)&S16[KA_K + (16 * tm + l15) * KA_QSX + g * 8];
    const int row0 = 16 * tm + 4 * g;
#pragma unroll
    for (int tn = 0; tn < 7; ++tn) {
      s16x8 bh = *(const s16x8*)&S16[KA_Q + (16 * tn + l15) * KA_QSX + g * 8];
      s16x8 bl = *(const s16x8*)&S16[KA_K + (16 * tn + l15) * KA_QSX + g * 8];
      f32x4 c = mfma16(al, bh, zero4);
      c = mfma16(ah, bl, c);
      c = mfma16(ah, bh, c);
      const int col = 16 * tn + l15;
#pragma unroll
      for (int r = 0; r < 4; ++r) {
        float d = fminf(1.f, fmaxf(-1.f, c[r]));
        u16 ch = f2b(d);
        const int row = row0 + r;
        S16[KA_CHI + row * KA_ASX + col] = ch;
        S16[KA_CLO + row * KA_ASX + col] = f2b(d - b2f(ch));
        if (row < 100 && col < 100) cgu[row * 100 + col] = ch;
      }
    }
  }
  __syncthreads();

  // ---- P5: z1 = (corr_hi+corr_lo) @ (t0_hi+t0_lo) + b1 -> HBM f32 + stats
  if (w < 7) {
    const int tm = w;
    float bj0 = b1[l15], bj1 = b1[16 + l15];
    float* zo = z1g + (size_t)b * 3200;
    f32x4 z0 = zero4, z1v = zero4;
#pragma unroll
    for (int kt = 0; kt < 4; ++kt) {
      s16x8 a_h = *(const s16x8*)&S16[KA_CHI + (16 * tm + l15) * KA_ASX + g * 8 + kt * 32];
      s16x8 a_l = *(const s16x8*)&S16[KA_CLO + (16 * tm + l15) * KA_ASX + g * 8 + kt * 32];
      s16x8 b0h = *(const s16x8*)&S16[KA_T0H + l15 * KA_ASX + g * 8 + kt * 32];
      s16x8 b0l = *(const s16x8*)&S16[KA_T0L + l15 * KA_ASX + g * 8 + kt * 32];
      s16x8 b1h = *(const s16x8*)&S16[KA_T0H + (16 + l15) * KA_ASX + g * 8 + kt * 32];
      s16x8 b1l = *(const s16x8*)&S16[KA_T0L + (16 + l15) * KA_ASX + g * 8 + kt * 32];
      z0 = mfma16(a_l, b0h, z0);  z0 = mfma16(a_h, b0l, z0);  z0 = mfma16(a_h, b0h, z0);
      z1v = mfma16(a_l, b1h, z1v); z1v = mfma16(a_h, b1l, z1v); z1v = mfma16(a_h, b1h, z1v);
    }
    const int row0 = 16 * tm + 4 * g;
#pragma unroll
    for (int r = 0; r < 4; ++r) {
      const int row = row0 + r;
      float v0 = z0[r] + bj0, v1 = z1v[r] + bj1;
      if (row < 100) { zo[row * 32 + l15] = v0; zo[row * 32 + 16 + l15] = v1; }
      float s = v0 + v1, ss = v0 * v0 + v1 * v1;
#pragma unroll
      for (int off = 1; off < 16; off <<= 1) {
        s += __shfl_xor(s, off, 16); ss += __shfl_xor(ss, off, 16);
      }
      if (row < 100 && l15 == 0) { atomicAdd(&stats1[row], s); atomicAdd(&stats1[100 + row], ss); }
    }
  }
}

// ---------------- KB: R2-proven VALU GCN step ----------------
template<int FIN, int FOUT>
__global__ __launch_bounds__(256, 2) void kb_kernel(
    const float* __restrict__ zin,
    const __hip_bfloat16* __restrict__ corr_g,
    const float* __restrict__ W, const float* __restrict__ bias,
    const float* __restrict__ stats_in, float* __restrict__ stats_out,
    float* __restrict__ zout)
{
  constexpr int LOGF  = (FOUT == 16) ? 4 : (FOUT == 8) ? 3 : (FOUT == 4) ? 2 : 1;
  constexpr int LOGFI = (FIN == 32) ? 5 : (FIN == 16) ? 4 : (FIN == 8) ? 3 : 2;
  constexpr int RP = 256 / FOUT;
  constexpr int NR = (100 + RP - 1) / RP;

  __shared__ float mS[100], vS[100];
  __shared__ float hL[100 * 33];
  __shared__ float tL[100 * (FOUT + 1)];
  __shared__ __align__(16) float clL[100 * 104];

  const int b = blockIdx.x, tid = threadIdx.x;

  // corr: HBM bf16 -> LDS f32 (unpack once, coalesced reads)
  {
    const u32* cgu = (const u32*)(corr_g + (size_t)b * 10000);
    for (int u = tid; u < 5000; u += 256) {
      int n = (u * 5243) >> 18;           // u/50 for u<5000
      int mm = (u - n * 50) << 1;
      u32 cc = cgu[u];
      clL[n * 104 + mm]     = blo(cc);
      clL[n * 104 + mm + 1] = bhi(cc);
    }
  }
  if (tid < 100) {
    float cnt  = 8192.0f * (float)FIN;
    float mean = stats_in[tid] / cnt;
    float var  = stats_in[100 + tid] / cnt - mean * mean;
    mS[tid] = mean;
    vS[tid] = rsqrtf(var + 1e-5f);
  }
  __syncthreads();

  // h = tanh(BN(z))
  {
    const float4* zb4 = (const float4*)(zin + (size_t)b * 100 * FIN);
    for (int i4 = tid; i4 < 25 * FIN; i4 += 256) {
      int n = i4 >> (LOGFI - 2);
      int c = (i4 << 2) & (FIN - 1);
      float4 z = zb4[i4];
      float mn = mS[n], iv = vS[n];
      hL[n * 33 + c + 0] = fast_tanh((z.x - mn) * iv);
      hL[n * 33 + c + 1] = fast_tanh((z.y - mn) * iv);
      hL[n * 33 + c + 2] = fast_tanh((z.z - mn) * iv);
      hL[n * 33 + c + 3] = fast_tanh((z.w - mn) * iv);
    }
  }
  __syncthreads();

  const int j  = tid & (FOUT - 1);
  const int nb = tid >> LOGF;

  // t = h @ W^T
  {
    float wreg[FIN];
#pragma unroll
    for (int c = 0; c < FIN; ++c) wreg[c] = W[j * FIN + c];
#pragma unroll
    for (int k = 0; k < NR; ++k) {
      int n = nb + k * RP;
      if (n < 100) {
        float a = 0.f;
#pragma unroll
        for (int c = 0; c < FIN; ++c) a = fmaf(hL[n * 33 + c], wreg[c], a);
        tL[n * (FOUT + 1) + j] = a;
      }
    }
  }
  __syncthreads();

  // z = corr @ t + bias ; stats for next layer
  {
    float acc[NR];
    float bj = bias[j];
#pragma unroll
    for (int k = 0; k < NR; ++k) acc[k] = bj;
    int nrow[NR];
#pragma unroll
    for (int k = 0; k < NR; ++k) nrow[k] = min(nb + k * RP, 99);  // clamp: dup row 99, masked at store
    const float4* c4 = (const float4*)clL;
#pragma unroll 5
    for (int m4 = 0; m4 < 25; ++m4) {
      float ta = tL[(m4 * 4 + 0) * (FOUT + 1) + j];
      float tb = tL[(m4 * 4 + 1) * (FOUT + 1) + j];
      float tc = tL[(m4 * 4 + 2) * (FOUT + 1) + j];
      float td = tL[(m4 * 4 + 3) * (FOUT + 1) + j];
#pragma unroll
      for (int k = 0; k < NR; ++k) {
        float4 c = c4[nrow[k] * 26 + m4];
        acc[k] = fmaf(c.x, ta, fmaf(c.y, tb, fmaf(c.z, tc, fmaf(c.w, td, acc[k]))));
      }
    }
    float* zo = zout + (size_t)b * 100 * FOUT;
#pragma unroll
    for (int k = 0; k < NR; ++k) {
      int n = nb + k * RP;
      if (n < 100) {
        float v = acc[k];
        zo[n * FOUT + j] = v;
        float s = v, ss = v * v;
#pragma unroll
        for (int off = FOUT >> 1; off; off >>= 1) {
          s  += __shfl_xor(s, off, FOUT);
          ss += __shfl_xor(ss, off, FOUT);
        }
        if (j == 0) {
          atomicAdd(&stats_out[n], s);
          atomicAdd(&stats_out[100 + n], ss);
        }
      }
    }
  }
}

// ---------------- KF: final BN+tanh + [200]->[2] head ----------------
__global__ __launch_bounds__(256) void kf_kernel(
    const float* __restrict__ z5, const float* __restrict__ stats5,
    const float* __restrict__ Wf, const float* __restrict__ bfv,
    float* __restrict__ out)
{
  __shared__ float mS[100], vS[100];
  const int tid = threadIdx.x;
  if (tid < 100) {
    float cnt  = 8192.0f * 2.0f;
    float mean = stats5[tid] / cnt;
    float var  = stats5[100 + tid] / cnt - mean * mean;
    mS[tid] = mean;
    vS[tid] = rsqrtf(var + 1e-5f);
  }
  __syncthreads();
  const int wvid = tid >> 6, lane = tid & 63;
  const int b = blockIdx.x * 4 + wvid;
  const float* zb = z5 + (size_t)b * 200;
  float a0 = 0.f, a1 = 0.f;
#pragma unroll
  for (int p = 0; p < 4; ++p) {
    int jj = lane + p * 64;
    if (jj < 200) {
      int n = jj >> 1;
      float hv = fast_tanh((zb[jj] - mS[n]) * vS[n]);
      a0 = fmaf(hv, Wf[jj], a0);
      a1 = fmaf(hv, Wf[200 + jj], a1);
    }
  }
#pragma unroll
  for (int off = 32; off; off >>= 1) {
    a0 += __shfl_xor(a0, off, 64);
    a1 += __shfl_xor(a1, off, 64);
  }
  if (lane == 0) {
    out[b * 2 + 0] = a0 + bfv[0];
    out[b * 2 + 1] = a1 + bfv[1];
  }
}

extern "C" void kernel_launch(void* const* d_in, const int* in_sizes, int n_in,
                              void* d_out, int out_size, void* d_ws, size_t ws_size,
                              hipStream_t stream)
{
  const float* x  = (const float*)d_in[0];
  const float* Wq = (const float*)d_in[1];
  const float* bq = (const float*)d_in[2];
  const float* Wk = (const float*)d_in[3];
  const float* bk = (const float*)d_in[4];
  const float* Wv = (const float*)d_in[5];
  const float* bv = (const float*)d_in[6];
  const float* W1 = (const float*)d_in[7];
  const float* b1 = (const float*)d_in[8];
  const float* W2 = (const float*)d_in[9];
  const float* b2 = (const float*)d_in[10];
  const float* W3 = (const float*)d_in[11];
  const float* b3 = (const float*)d_in[12];
  const float* W4 = (const float*)d_in[13];
  const float* b4 = (const float*)d_in[14];
  const float* W5 = (const float*)d_in[15];
  const float* b5 = (const float*)d_in[16];
  const float* Wf = (const float*)d_in[17];
  const float* bf = (const float*)d_in[18];
  float* out = (float*)d_out;

  char* ws = (char*)d_ws;
  // ws: corr bf16 [8192,100,100] @0 ; zA f32 [8192,100,32] @163840000 ;
  //     zB f32 [8192,100,16] @268697600 ; stats 5*[200] f32 @321126400
  const size_t NEED = 321130400ull;
  if (ws_size < NEED) return;

  __hip_bfloat16* corr_g = (__hip_bfloat16*)ws;
  float* zA    = (float*)(ws + 163840000ull);
  float* zB    = (float*)(ws + 268697600ull);
  float* stats = (float*)(ws + 321126400ull);

  (void)hipMemsetAsync(stats, 0, 5 * 200 * sizeof(float), stream);

  ka_kernel<<<8192, 512, 0, stream>>>(x, Wq, bq, Wk, bk, Wv, bv, W1, b1,
                                      corr_g, zA, stats);
  kb_kernel<32, 16><<<8192, 256, 0, stream>>>(zA, corr_g, W2, b2, stats,       stats + 200, zB);
  kb_kernel<16,  8><<<8192, 256, 0, stream>>>(zB, corr_g, W3, b3, stats + 200, stats + 400, zA);
  kb_kernel< 8,  4><<<8192, 256, 0, stream>>>(zA, corr_g, W4, b4, stats + 400, stats + 600, zB);
  kb_kernel< 4,  2><<<8192, 256, 0, stream>>>(zB, corr_g, W5, b5, stats + 600, stats + 800, zA);
  kf_kernel<<<2048, 256, 0, stream>>>(zA, stats + 800, Wf, bf, out);
}

// Round 8
// 3984.128 us; speedup vs baseline: 2.1301x; 1.0087x over previous
//
#include <hip/hip_runtime.h>
#include <hip/hip_bf16.h>

// whole_network: attention -> corrcoef -> 5x (GCN + BatchNorm(node) + tanh) -> linear head
// B=8192, N=100 (pad 112), T=64.
// KA: P1 QKV/t0 via hi/lo MFMA (W-frags in regs from global, x hi/lo LDS);
//     P2 S=QK^T MFMA on single-bf16 Q,K (== R2 math); P3/P4/P5 f32 VALU (R2-proven).
//     LDS 80928 B -> 2 blocks/CU at 512 threads.
// KB: R2/R7-proven structure; corr kept bf16-in-LDS, unpacked in inner loop -> 41.6 KB, 3 blocks/CU.

typedef unsigned int u32;
typedef unsigned short u16;
typedef float f32x4 __attribute__((ext_vector_type(4)));
typedef short s16x8 __attribute__((ext_vector_type(8)));

__device__ __forceinline__ f32x4 mfma16(s16x8 a, s16x8 b, f32x4 c) {
  return __builtin_amdgcn_mfma_f32_16x16x32_bf16(a, b, c, 0, 0, 0);
}
__device__ __forceinline__ u16 f2b(float f) {
  __hip_bfloat16 h = __float2bfloat16(f);
  u16 u; __builtin_memcpy(&u, &h, 2); return u;
}
__device__ __forceinline__ float b2f(u16 u) { return __uint_as_float((u32)u << 16); }
__device__ __forceinline__ float blo(u32 u) { return __uint_as_float(u << 16); }
__device__ __forceinline__ float bhi(u32 u) { return __uint_as_float(u & 0xffff0000u); }
__device__ __forceinline__ u32 pack_hi2(float a, float b) { return (u32)f2b(a) | ((u32)f2b(b) << 16); }
__device__ __forceinline__ u32 pack_lo2(float a, float b) {
  return (u32)f2b(a - b2f(f2b(a))) | ((u32)f2b(b - b2f(f2b(b))) << 16);
}
__device__ __forceinline__ float fast_tanh(float x) {
  float e = __expf(2.0f * x);
  return 1.0f - 2.0f * __builtin_amdgcn_rcpf(e + 1.0f);
}

// ---------------- KA LDS map (BYTE offsets), total 80928 B => 2 blocks/CU ----------------
// x_hi u16[112][72] @0 (16128), x_lo @16128 (16128)      (P0-P1; dead after P1)
// A/corr f32[112][100] @0 (44800)                         (P2..P5, overlays x)
// Q u16[112][36] @44800 (8064) ; K u16[112][36] @52864 (8064)   (dead after P2)
// chat f32[100][33] @44800 (13200, overlays Q + head of K)      (P3..P4)
// V  u16[100][34] @60928 (6800)
// t0 f32[100][33] @67728 (13200)
#define KA_XLO_B  16128
#define KA_Q_B    44800
#define KA_K_B    52864
#define KA_CHAT_B 44800
#define KA_V_B    60928
#define KA_T0_B   67728
#define KA_SMEM_B 80928

__global__ __launch_bounds__(512, 4) void ka_kernel(
    const float* __restrict__ x,
    const float* __restrict__ Wq, const float* __restrict__ bq,
    const float* __restrict__ Wk, const float* __restrict__ bk,
    const float* __restrict__ Wv, const float* __restrict__ bv,
    const float* __restrict__ W1, const float* __restrict__ b1,
    __hip_bfloat16* __restrict__ corr_g,   // [B,100,100] bf16
    float* __restrict__ z1g,               // [B,100,32] f32
    float* __restrict__ stats1)            // [200]
{
  __shared__ __align__(16) char smem[KA_SMEM_B];
  u16*   xh   = (u16*)smem;
  u16*   xl   = (u16*)(smem + KA_XLO_B);
  float* Af   = (float*)smem;
  u16*   Qs   = (u16*)(smem + KA_Q_B);
  u16*   Ks   = (u16*)(smem + KA_K_B);
  float* chat = (float*)(smem + KA_CHAT_B);
  u16*   Vb   = (u16*)(smem + KA_V_B);
  float* t0   = (float*)(smem + KA_T0_B);

  const int b = blockIdx.x, tid = threadIdx.x;
  const int w = tid >> 6, l = tid & 63, l15 = l & 15, g = l >> 4;
  const f32x4 zero4 = {0.f, 0.f, 0.f, 0.f};

  // ---- P0: stage x hi/lo bf16 (rows >=100 zero)
  {
    const float2* xg2 = (const float2*)(x + (size_t)b * 6400);
    for (int i = tid; i < 112 * 32; i += 512) {
      int r = i >> 5, c2 = i & 31;
      float vx = 0.f, vy = 0.f;
      if (r < 100) { float2 v = xg2[r * 32 + c2]; vx = v.x; vy = v.y; }
      ((u32*)xh)[r * 36 + c2] = pack_hi2(vx, vy);
      ((u32*)xl)[r * 36 + c2] = pack_lo2(vx, vy);
    }
  }
  __syncthreads();

  // ---- P1: [Q|K|V|t0] = x @ Wcat^T, 3-term hi/lo MFMA; W-frags in regs from global
  {
    const int mi = w >> 1, half = w & 1;
    const int j = 16 * half + l15;
    const float* Wp = (mi == 0) ? Wq : (mi == 1) ? Wk : (mi == 2) ? Wv : W1;
    float bias = (mi == 0) ? bq[j] : (mi == 1) ? bk[j] : (mi == 2) ? bv[j] : 0.f;
    s16x8 bh[2], bl[2];
#pragma unroll
    for (int kt = 0; kt < 2; ++kt) {
      const float* wr = Wp + j * 64 + kt * 32 + g * 8;
#pragma unroll
      for (int e = 0; e < 8; ++e) {
        float wv = wr[e];
        u16 hh = f2b(wv);
        bh[kt][e] = (short)hh;
        bl[kt][e] = (short)f2b(wv - b2f(hh));
      }
    }
    for (int tm = 0; tm < 7; ++tm) {
      f32x4 acc = zero4;
#pragma unroll
      for (int kt = 0; kt < 2; ++kt) {
        s16x8 ah = *(const s16x8*)&xh[(16 * tm + l15) * 72 + kt * 32 + g * 8];
        s16x8 al = *(const s16x8*)&xl[(16 * tm + l15) * 72 + kt * 32 + g * 8];
        acc = mfma16(al, bh[kt], acc);
        acc = mfma16(ah, bl[kt], acc);
        acc = mfma16(ah, bh[kt], acc);
      }
      const int row0 = 16 * tm + 4 * g;
#pragma unroll
      for (int r = 0; r < 4; ++r) {
        int row = row0 + r;
        float v = acc[r] + bias;
        if (mi == 0)      Qs[row * 36 + j] = f2b(v);
        else if (mi == 1) Ks[row * 36 + j] = f2b(v);
        else if (mi == 2) { if (row < 100) Vb[row * 34 + j] = f2b(v); }
        else              { if (row < 100) t0[row * 33 + j] = v; }
      }
    }
  }
  __syncthreads();

  // ---- P2: S = Q K^T (MFMA, single-bf16 == R2 math), softmax -> A f32 (overlays x)
  if (w < 7) {
    const int tm = w;
    s16x8 aq = *(const s16x8*)&Qs[(16 * tm + l15) * 36 + g * 8];
    f32x4 sc[7];
#pragma unroll
    for (int tn = 0; tn < 7; ++tn) {
      s16x8 bb = *(const s16x8*)&Ks[(16 * tn + l15) * 36 + g * 8];
      sc[tn] = mfma16(aq, bb, zero4);
    }
    const int row0 = 16 * tm + 4 * g;
#pragma unroll
    for (int r = 0; r < 4; ++r) {
      const int row = row0 + r;
      float v[7];
#pragma unroll
      for (int tn = 0; tn < 7; ++tn) v[tn] = sc[tn][r];
      if (l15 >= 4) v[6] = -3.0e38f;               // mask cols >= 100
      float m = v[0];
#pragma unroll
      for (int tn = 1; tn < 7; ++tn) m = fmaxf(m, v[tn]);
#pragma unroll
      for (int off = 1; off < 16; off <<= 1) m = fmaxf(m, __shfl_xor(m, off, 16));
      float e[7], s = 0.f;
#pragma unroll
      for (int tn = 0; tn < 7; ++tn) { e[tn] = __expf((v[tn] - m) * 0.03125f); s += e[tn]; }
#pragma unroll
      for (int off = 1; off < 16; off <<= 1) s += __shfl_xor(s, off, 16);
      float rr = __builtin_amdgcn_rcpf(s);
      bool ok = row < 100;
#pragma unroll
      for (int tn = 0; tn < 7; ++tn) {
        int col = 16 * tn + l15;
        float a = ok ? e[tn] * rr : 0.f;
        if (col < 100) Af[row * 100 + col] = a;
      }
    }
  }
  __syncthreads();

  // ---- P3: feat = A @ V (f32 VALU, R2 pattern); row-normalize -> chat f32 (overlays Q/K)
  {
    const int j = tid & 31, gr = tid >> 5;       // gr 0..15
    float fa[7];
#pragma unroll
    for (int k = 0; k < 7; ++k) fa[k] = 0.f;
    const float4* A4 = (const float4*)Af;        // row stride 25 float4
#pragma unroll 5
    for (int m4 = 0; m4 < 25; ++m4) {
      float v0 = b2f(Vb[(4 * m4 + 0) * 34 + j]);
      float v1 = b2f(Vb[(4 * m4 + 1) * 34 + j]);
      float v2 = b2f(Vb[(4 * m4 + 2) * 34 + j]);
      float v3 = b2f(Vb[(4 * m4 + 3) * 34 + j]);
#pragma unroll
      for (int k = 0; k < 7; ++k) {
        float4 a = A4[(gr + 16 * k) * 25 + m4];
        fa[k] = fmaf(a.x, v0, fmaf(a.y, v1, fmaf(a.z, v2, fmaf(a.w, v3, fa[k]))));
      }
    }
#pragma unroll
    for (int k = 0; k < 7; ++k) {
      int n = gr + 16 * k;
      float vv = fa[k];
      float s = vv;
#pragma unroll
      for (int off = 16; off; off >>= 1) s += __shfl_xor(s, off, 32);
      float mean = s * 0.03125f;
      float xc = vv - mean;
      float q = xc * xc;
#pragma unroll
      for (int off = 16; off; off >>= 1) q += __shfl_xor(q, off, 32);
      float inv = rsqrtf(q + 1e-30f);
      if (n < 100) chat[n * 33 + j] = xc * inv;
    }
  }
  __syncthreads();

  // ---- P4: corr = clip(chat chat^T) (f32 VALU, R2 pattern) -> Af (overlay) + HBM bf16
  {
    float c0a[13], c1a[13];
#pragma unroll
    for (int k = 0; k < 13; ++k) { c0a[k] = 0.f; c1a[k] = 0.f; }
    const float* ca = chat + l * 33;
    const float* cb = chat + (l + 64) * 33;      // rows >=100 garbage, masked below
    const bool mok = l < 36;
#pragma unroll 4
    for (int t = 0; t < 32; ++t) {
      float a = ca[t], bb2 = cb[t];
#pragma unroll
      for (int k = 0; k < 13; ++k) {
        float q = chat[(w + 8 * k) * 33 + t];    // rows >=100 garbage, masked below
        c0a[k] = fmaf(q, a, c0a[k]);
        c1a[k] = fmaf(q, bb2, c1a[k]);
      }
    }
    u16* cgu = (u16*)(corr_g + (size_t)b * 10000);
#pragma unroll
    for (int k = 0; k < 13; ++k) {
      int row = w + 8 * k;
      if (row < 100) {
        float d0 = fminf(1.f, fmaxf(-1.f, c0a[k]));
        Af[row * 100 + l] = d0;
        cgu[row * 100 + l] = f2b(d0);
        if (mok) {
          float d1 = fminf(1.f, fmaxf(-1.f, c1a[k]));
          Af[row * 100 + 64 + l] = d1;
          cgu[row * 100 + 64 + l] = f2b(d1);
        }
      }
    }
  }
  __syncthreads();

  // ---- P5: z1 = corr @ t0 + b1 (f32 VALU, R2 pattern) + stats
  {
    const int j = tid & 31, gr = tid >> 5;
    float acc[7];
    float bj = b1[j];
#pragma unroll
    for (int k = 0; k < 7; ++k) acc[k] = bj;
    int nrow[7];
#pragma unroll
    for (int k = 0; k < 7; ++k) nrow[k] = min(gr + 16 * k, 99);
    const float4* c4 = (const float4*)Af;
#pragma unroll 5
    for (int m4 = 0; m4 < 25; ++m4) {
      float ta = t0[(4 * m4 + 0) * 33 + j];
      float tb = t0[(4 * m4 + 1) * 33 + j];
      float tc = t0[(4 * m4 + 2) * 33 + j];
      float td = t0[(4 * m4 + 3) * 33 + j];
#pragma unroll
      for (int k = 0; k < 7; ++k) {
        float4 c = c4[nrow[k] * 25 + m4];
        acc[k] = fmaf(c.x, ta, fmaf(c.y, tb, fmaf(c.z, tc, fmaf(c.w, td, acc[k]))));
      }
    }
    float* zo = z1g + (size_t)b * 3200;
#pragma unroll
    for (int k = 0; k < 7; ++k) {
      int n = gr + 16 * k;
      if (n < 100) {
        float v = acc[k];
        zo[n * 32 + j] = v;
        float s = v, ss = v * v;
#pragma unroll
        for (int off = 16; off; off >>= 1) {
          s  += __shfl_xor(s, off, 32);
          ss += __shfl_xor(ss, off, 32);
        }
        if (j == 0) {
          atomicAdd(&stats1[n], s);
          atomicAdd(&stats1[100 + n], ss);
        }
      }
    }
  }
}

// ---------------- KB: R2/R7-proven GCN step; corr bf16-in-LDS, unpack in inner loop ----------------
template<int FIN, int FOUT>
__global__ __launch_bounds__(256, 3) void kb_kernel(
    const float* __restrict__ zin,
    const __hip_bfloat16* __restrict__ corr_g,
    const float* __restrict__ W, const float* __restrict__ bias,
    const float* __restrict__ stats_in, float* __restrict__ stats_out,
    float* __restrict__ zout)
{
  constexpr int LOGF  = (FOUT == 16) ? 4 : (FOUT == 8) ? 3 : (FOUT == 4) ? 2 : 1;
  constexpr int LOGFI = (FIN == 32) ? 5 : (FIN == 16) ? 4 : (FIN == 8) ? 3 : 2;
  constexpr int RP = 256 / FOUT;
  constexpr int NR = (100 + RP - 1) / RP;

  __shared__ u32 clLu[100 * 52];                 // corr bf16 pairs, [100][52] u32 (50 used)
  __shared__ float mS[100], vS[100];
  __shared__ float hL[100 * 33];
  __shared__ float tL[100 * (FOUT + 1)];

  const int b = blockIdx.x, tid = threadIdx.x;

  // corr: HBM bf16 -> LDS (u32 pairs, no unpack)
  {
    const u32* cgu = (const u32*)(corr_g + (size_t)b * 10000);
    for (int i = tid; i < 5000; i += 256) {
      int n = (i * 5243) >> 18;                  // i/50 for i<5000
      int mm = i - n * 50;
      clLu[n * 52 + mm] = cgu[i];
    }
  }
  if (tid < 100) {
    float cnt  = 8192.0f * (float)FIN;
    float mean = stats_in[tid] / cnt;
    float var  = stats_in[100 + tid] / cnt - mean * mean;
    mS[tid] = mean;
    vS[tid] = rsqrtf(var + 1e-5f);
  }
  __syncthreads();

  // h = tanh(BN(z))
  {
    const float4* zb4 = (const float4*)(zin + (size_t)b * 100 * FIN);
    for (int i4 = tid; i4 < 25 * FIN; i4 += 256) {
      int n = i4 >> (LOGFI - 2);
      int c = (i4 << 2) & (FIN - 1);
      float4 z = zb4[i4];
      float mn = mS[n], iv = vS[n];
      hL[n * 33 + c + 0] = fast_tanh((z.x - mn) * iv);
      hL[n * 33 + c + 1] = fast_tanh((z.y - mn) * iv);
      hL[n * 33 + c + 2] = fast_tanh((z.z - mn) * iv);
      hL[n * 33 + c + 3] = fast_tanh((z.w - mn) * iv);
    }
  }
  __syncthreads();

  const int j  = tid & (FOUT - 1);
  const int nb = tid >> LOGF;

  // t = h @ W^T
  {
    float wreg[FIN];
#pragma unroll
    for (int c = 0; c < FIN; ++c) wreg[c] = W[j * FIN + c];
#pragma unroll
    for (int k = 0; k < NR; ++k) {
      int n = nb + k * RP;
      if (n < 100) {
        float a = 0.f;
#pragma unroll
        for (int c = 0; c < FIN; ++c) a = fmaf(hL[n * 33 + c], wreg[c], a);
        tL[n * (FOUT + 1) + j] = a;
      }
    }
  }
  __syncthreads();

  // z = corr @ t + bias ; stats for next layer
  {
    float acc[NR];
    float bj = bias[j];
#pragma unroll
    for (int k = 0; k < NR; ++k) acc[k] = bj;
    int nrow[NR];
#pragma unroll
    for (int k = 0; k < NR; ++k) nrow[k] = min(nb + k * RP, 99);
#pragma unroll 5
    for (int m4 = 0; m4 < 25; ++m4) {
      float ta = tL[(m4 * 4 + 0) * (FOUT + 1) + j];
      float tb = tL[(m4 * 4 + 1) * (FOUT + 1) + j];
      float tc = tL[(m4 * 4 + 2) * (FOUT + 1) + j];
      float td = tL[(m4 * 4 + 3) * (FOUT + 1) + j];
#pragma unroll
      for (int k = 0; k < NR; ++k) {
        u32 p0 = clLu[nrow[k] * 52 + 2 * m4];
        u32 p1 = clLu[nrow[k] * 52 + 2 * m4 + 1];
        acc[k] = fmaf(blo(p0), ta, fmaf(bhi(p0), tb,
                 fmaf(blo(p1), tc, fmaf(bhi(p1), td, acc[k]))));
      }
    }
    float* zo = zout + (size_t)b * 100 * FOUT;
#pragma unroll
    for (int k = 0; k < NR; ++k) {
      int n = nb + k * RP;
      if (n < 100) {
        float v = acc[k];
        zo[n * FOUT + j] = v;
        float s = v, ss = v * v;
#pragma unroll
        for (int off = FOUT >> 1; off; off >>= 1) {
          s  += __shfl_xor(s, off, FOUT);
          ss += __shfl_xor(ss, off, FOUT);
        }
        if (j == 0) {
          atomicAdd(&stats_out[n], s);
          atomicAdd(&stats_out[100 + n], ss);
        }
      }
    }
  }
}

// ---------------- KF: final BN+tanh + [200]->[2] head ----------------
__global__ __launch_bounds__(256) void kf_kernel(
    const float* __restrict__ z5, const float* __restrict__ stats5,
    const float* __restrict__ Wf, const float* __restrict__ bfv,
    float* __restrict__ out)
{
  __shared__ float mS[100], vS[100];
  const int tid = threadIdx.x;
  if (tid < 100) {
    float cnt  = 8192.0f * 2.0f;
    float mean = stats5[tid] / cnt;
    float var  = stats5[100 + tid] / cnt - mean * mean;
    mS[tid] = mean;
    vS[tid] = rsqrtf(var + 1e-5f);
  }
  __syncthreads();
  const int wvid = tid >> 6, lane = tid & 63;
  const int b = blockIdx.x * 4 + wvid;
  const float* zb = z5 + (size_t)b * 200;
  float a0 = 0.f, a1 = 0.f;
#pragma unroll
  for (int p = 0; p < 4; ++p) {
    int jj = lane + p * 64;
    if (jj < 200) {
      int n = jj >> 1;
      float hv = fast_tanh((zb[jj] - mS[n]) * vS[n]);
      a0 = fmaf(hv, Wf[jj], a0);
      a1 = fmaf(hv, Wf[200 + jj], a1);
    }
  }
#pragma unroll
  for (int off = 32; off; off >>= 1) {
    a0 += __shfl_xor(a0, off, 64);
    a1 += __shfl_xor(a1, off, 64);
  }
  if (lane == 0) {
    out[b * 2 + 0] = a0 + bfv[0];
    out[b * 2 + 1] = a1 + bfv[1];
  }
}

extern "C" void kernel_launch(void* const* d_in, const int* in_sizes, int n_in,
                              void* d_out, int out_size, void* d_ws, size_t ws_size,
                              hipStream_t stream)
{
  const float* x  = (const float*)d_in[0];
  const float* Wq = (const float*)d_in[1];
  const float* bq = (const float*)d_in[2];
  const float* Wk = (const float*)d_in[3];
  const float* bk = (const float*)d_in[4];
  const float* Wv = (const float*)d_in[5];
  const float* bv = (const float*)d_in[6];
  const float* W1 = (const float*)d_in[7];
  const float* b1 = (const float*)d_in[8];
  const float* W2 = (const float*)d_in[9];
  const float* b2 = (const float*)d_in[10];
  const float* W3 = (const float*)d_in[11];
  const float* b3 = (const float*)d_in[12];
  const float* W4 = (const float*)d_in[13];
  const float* b4 = (const float*)d_in[14];
  const float* W5 = (const float*)d_in[15];
  const float* b5 = (const float*)d_in[16];
  const float* Wf = (const float*)d_in[17];
  const float* bf = (const float*)d_in[18];
  float* out = (float*)d_out;

  char* ws = (char*)d_ws;
  // ws: corr bf16 [8192,100,100] @0 ; zA f32 [8192,100,32] @163840000 ;
  //     zB f32 [8192,100,16] @268697600 ; stats 5*[200] f32 @321126400
  const size_t NEED = 321130400ull;
  if (ws_size < NEED) return;

  __hip_bfloat16* corr_g = (__hip_bfloat16*)ws;
  float* zA    = (float*)(ws + 163840000ull);
  float* zB    = (float*)(ws + 268697600ull);
  float* stats = (float*)(ws + 321126400ull);

  (void)hipMemsetAsync(stats, 0, 5 * 200 * sizeof(float), stream);

  ka_kernel<<<8192, 512, 0, stream>>>(x, Wq, bq, Wk, bk, Wv, bv, W1, b1,
                                      corr_g, zA, stats);
  kb_kernel<32, 16><<<8192, 256, 0, stream>>>(zA, corr_g, W2, b2, stats,       stats + 200, zB);
  kb_kernel<16,  8><<<8192, 256, 0, stream>>>(zB, corr_g, W3, b3, stats + 200, stats + 400, zA);
  kb_kernel< 8,  4><<<8192, 256, 0, stream>>>(zA, corr_g, W4, b4, stats + 400, stats + 600, zB);
  kb_kernel< 4,  2><<<8192, 256, 0, stream>>>(zB, corr_g, W5, b5, stats + 600, stats + 800, zA);
  kf_kernel<<<2048, 256, 0, stream>>>(zA, stats + 800, Wf, bf, out);
}

// Round 11
// 3857.644 us; speedup vs baseline: 2.1999x; 1.0328x over previous
//
#include <hip/hip_runtime.h>
#include <hip/hip_bf16.h>

// whole_network: attention -> corrcoef -> 5x (GCN + BatchNorm(node) + tanh) -> linear head
// B=8192, N=100 (pad 112), T=64.
// KA: all-MFMA pipeline at 2 blocks/CU (LDS 78336 via aggressive phase overlays;
//     t0 carried in registers across P4). hi/lo double-bf16 everywhere except A (single).
// KB/KF: R7/R8-proven structures.
// (Resubmission #3 of the R9 kernel: R9/R10 benches died to a pre-existing dead pod,
//  identical signature to R1's flake; kernel never executed.)

typedef unsigned int u32;
typedef unsigned short u16;
typedef float f32x4 __attribute__((ext_vector_type(4)));
typedef short s16x8 __attribute__((ext_vector_type(8)));

__device__ __forceinline__ f32x4 mfma16(s16x8 a, s16x8 b, f32x4 c) {
  return __builtin_amdgcn_mfma_f32_16x16x32_bf16(a, b, c, 0, 0, 0);
}
__device__ __forceinline__ u16 f2b(float f) {
  __hip_bfloat16 h = __float2bfloat16(f);
  u16 u; __builtin_memcpy(&u, &h, 2); return u;
}
__device__ __forceinline__ float b2f(u16 u) { return __uint_as_float((u32)u << 16); }
__device__ __forceinline__ float blo(u32 u) { return __uint_as_float(u << 16); }
__device__ __forceinline__ float bhi(u32 u) { return __uint_as_float(u & 0xffff0000u); }
__device__ __forceinline__ u32 pack_hi2(float a, float b) { return (u32)f2b(a) | ((u32)f2b(b) << 16); }
__device__ __forceinline__ u32 pack_lo2(float a, float b) {
  return (u32)f2b(a - b2f(f2b(a))) | ((u32)f2b(b - b2f(f2b(b))) << 16);
}
__device__ __forceinline__ float fast_tanh(float x) {
  float e = __expf(2.0f * x);
  return 1.0f - 2.0f * __builtin_amdgcn_rcpf(e + 1.0f);
}

// ---------------- KA LDS map (BYTE offsets), total 78336 => 2 blocks/CU ----------------
// P0-P1: x_hi u16[112][72]@0, x_lo@16128 (ends 32256)
// P2-P3: A  u16[112][136]@0 (30464, overlays x)
// P4b-P5: corr_hi u16[112][136]@0, corr_lo@30464 (ends 60928)
// P1-P2: Q u16[112][36]@32256, K@40320 (ends 48384)
// P3-P4a: chat_hi@32256, chat_lo@40320 (overlay Q/K)
// P1-P3: Vt u16[32][136]@48384 (8704, ends 57088)
// P4b-P5: t0_hi u16[32][136]@60928, t0_lo@69632 (ends 78336)
#define KA_XHI_B   0
#define KA_XLO_B   16128
#define KA_A_B     0
#define KA_QS_B    32256
#define KA_KS_B    40320
#define KA_CHH_B   32256
#define KA_CHL_B   40320
#define KA_VT_B    48384
#define KA_CRH_B   0
#define KA_CRL_B   30464
#define KA_T0H_B   60928
#define KA_T0L_B   69632
#define KA_SMEM_B  78336

__global__ __launch_bounds__(512, 4) void ka_kernel(
    const float* __restrict__ x,
    const float* __restrict__ Wq, const float* __restrict__ bq,
    const float* __restrict__ Wk, const float* __restrict__ bk,
    const float* __restrict__ Wv, const float* __restrict__ bv,
    const float* __restrict__ W1, const float* __restrict__ b1,
    __hip_bfloat16* __restrict__ corr_g,   // [B,100,100] bf16
    float* __restrict__ z1g,               // [B,100,32] f32
    float* __restrict__ stats1)            // [200]
{
  __shared__ __align__(16) char smem[KA_SMEM_B];
  u16* xh  = (u16*)(smem + KA_XHI_B);
  u16* xl  = (u16*)(smem + KA_XLO_B);
  u16* A16 = (u16*)(smem + KA_A_B);
  u16* Qs  = (u16*)(smem + KA_QS_B);
  u16* Ks  = (u16*)(smem + KA_KS_B);
  u16* chh = (u16*)(smem + KA_CHH_B);
  u16* chl = (u16*)(smem + KA_CHL_B);
  u16* Vt  = (u16*)(smem + KA_VT_B);
  u16* crh = (u16*)(smem + KA_CRH_B);
  u16* crl = (u16*)(smem + KA_CRL_B);
  u16* t0h = (u16*)(smem + KA_T0H_B);
  u16* t0l = (u16*)(smem + KA_T0L_B);

  const int b = blockIdx.x, tid = threadIdx.x;
  const int w = tid >> 6, l15 = tid & 15, g = (tid & 63) >> 4;
  const f32x4 zero4 = {0.f, 0.f, 0.f, 0.f};

  float t0r[28];     // t0 values (waves 6,7 only), live P1 -> P4b
  float cr[7][4];    // corr fragments (waves 0..6), live P4a -> P4b

  // ---- P0: stage x hi/lo (rows >=100 zero); zero Vt pad cols 112..127
  {
    const float2* xg2 = (const float2*)(x + (size_t)b * 6400);
    for (int i = tid; i < 112 * 32; i += 512) {
      int r = i >> 5, c2 = i & 31;
      float vx = 0.f, vy = 0.f;
      if (r < 100) { float2 v = xg2[r * 32 + c2]; vx = v.x; vy = v.y; }
      ((u32*)xh)[r * 36 + c2] = pack_hi2(vx, vy);
      ((u32*)xl)[r * 36 + c2] = pack_lo2(vx, vy);
    }
    if (tid < 256) {
      int j = tid >> 3, ii = tid & 7;
      ((u32*)Vt)[j * 68 + 56 + ii] = 0;
    }
  }
  __syncthreads();

  // ---- P1: [Q|K|V|t0] = x @ Wcat^T, 3-term hi/lo MFMA; W-frags in regs from global
  {
    const int mi = w >> 1, half = w & 1;
    const int j = 16 * half + l15;
    const float* Wp = (mi == 0) ? Wq : (mi == 1) ? Wk : (mi == 2) ? Wv : W1;
    float bias = (mi == 0) ? bq[j] : (mi == 1) ? bk[j] : (mi == 2) ? bv[j] : 0.f;
    s16x8 bhf[2], blf[2];
#pragma unroll
    for (int kt = 0; kt < 2; ++kt) {
      const float* wr = Wp + j * 64 + kt * 32 + g * 8;
#pragma unroll
      for (int e = 0; e < 8; ++e) {
        float wv = wr[e];
        u16 hh = f2b(wv);
        bhf[kt][e] = (short)hh;
        blf[kt][e] = (short)f2b(wv - b2f(hh));
      }
    }
#pragma unroll
    for (int tm = 0; tm < 7; ++tm) {
      f32x4 acc = zero4;
#pragma unroll
      for (int kt = 0; kt < 2; ++kt) {
        s16x8 ah = *(const s16x8*)&xh[(16 * tm + l15) * 72 + kt * 32 + g * 8];
        s16x8 al = *(const s16x8*)&xl[(16 * tm + l15) * 72 + kt * 32 + g * 8];
        acc = mfma16(al, bhf[kt], acc);
        acc = mfma16(ah, blf[kt], acc);
        acc = mfma16(ah, bhf[kt], acc);
      }
      const int row0 = 16 * tm + 4 * g;
#pragma unroll
      for (int r = 0; r < 4; ++r) {
        int row = row0 + r;
        float v = acc[r] + bias;
        if (mi == 0)      Qs[row * 36 + j] = f2b(v);
        else if (mi == 1) Ks[row * 36 + j] = f2b(v);
        else if (mi == 2) Vt[j * 136 + row] = f2b(v);      // transposed; rows>=100 = bias (A=0 there)
        else              t0r[tm * 4 + r] = v;             // keep in regs (rows>=100 exactly 0)
      }
    }
  }
  __syncthreads();

  // ---- P2: S = Q K^T (MFMA), softmax -> A single-bf16 [112][136] (overlays x)
  if (w < 7) {
    const int tm = w;
    s16x8 aq = *(const s16x8*)&Qs[(16 * tm + l15) * 36 + g * 8];
    f32x4 sc[7];
#pragma unroll
    for (int tn = 0; tn < 7; ++tn) {
      s16x8 bb = *(const s16x8*)&Ks[(16 * tn + l15) * 36 + g * 8];
      sc[tn] = mfma16(aq, bb, zero4);
    }
    const int row0 = 16 * tm + 4 * g;
#pragma unroll
    for (int r = 0; r < 4; ++r) {
      const int row = row0 + r;
      float v[7];
#pragma unroll
      for (int tn = 0; tn < 7; ++tn) v[tn] = sc[tn][r];
      if (l15 >= 4) v[6] = -3.0e38f;               // mask cols >= 100
      float m = v[0];
#pragma unroll
      for (int tn = 1; tn < 7; ++tn) m = fmaxf(m, v[tn]);
#pragma unroll
      for (int off = 1; off < 16; off <<= 1) m = fmaxf(m, __shfl_xor(m, off, 16));
      float e[7], s = 0.f;
#pragma unroll
      for (int tn = 0; tn < 7; ++tn) { e[tn] = __expf((v[tn] - m) * 0.03125f); s += e[tn]; }
#pragma unroll
      for (int off = 1; off < 16; off <<= 1) s += __shfl_xor(s, off, 16);
      float rr = __builtin_amdgcn_rcpf(s);
      bool ok = row < 100;
#pragma unroll
      for (int tn = 0; tn < 7; ++tn) {
        float a = ok ? e[tn] * rr : 0.f;
        A16[row * 136 + 16 * tn + l15] = f2b(a);
      }
      if (l15 < 8) ((u32*)A16)[row * 68 + 56 + l15] = 0;   // cols 112..127 := 0
    }
  }
  __syncthreads();

  // ---- P3: feat = A @ V (MFMA, K=128); row-normalize -> chat hi/lo (overlay Q/K)
  if (w < 7) {
    const int tm = w;
    f32x4 f0 = zero4, f1 = zero4;
#pragma unroll
    for (int kt = 0; kt < 4; ++kt) {
      s16x8 a   = *(const s16x8*)&A16[(16 * tm + l15) * 136 + kt * 32 + g * 8];
      s16x8 b0  = *(const s16x8*)&Vt[l15 * 136 + kt * 32 + g * 8];
      s16x8 b1v = *(const s16x8*)&Vt[(16 + l15) * 136 + kt * 32 + g * 8];
      f0 = mfma16(a, b0, f0);
      f1 = mfma16(a, b1v, f1);
    }
    const int row0 = 16 * tm + 4 * g;
#pragma unroll
    for (int r = 0; r < 4; ++r) {
      float v0 = f0[r], v1 = f1[r];
      float s = v0 + v1;
#pragma unroll
      for (int off = 1; off < 16; off <<= 1) s += __shfl_xor(s, off, 16);
      float mean = s * 0.03125f;
      float xc0 = v0 - mean, xc1 = v1 - mean;
      float q = xc0 * xc0 + xc1 * xc1;
#pragma unroll
      for (int off = 1; off < 16; off <<= 1) q += __shfl_xor(q, off, 16);
      float inv = rsqrtf(q + 1e-30f);              // zero rows stay exactly 0
      const int row = row0 + r;
      float c0 = xc0 * inv, c1 = xc1 * inv;
      u16 h0 = f2b(c0), h1 = f2b(c1);
      chh[row * 36 + l15]      = h0;
      chh[row * 36 + 16 + l15] = h1;
      chl[row * 36 + l15]      = f2b(c0 - b2f(h0));
      chl[row * 36 + 16 + l15] = f2b(c1 - b2f(h1));
    }
  }
  __syncthreads();

  // ---- P4a: corr = clip(3-term chat@chat^T) -> regs + HBM bf16
  if (w < 7) {
    u16* cgu = (u16*)(corr_g + (size_t)b * 10000);
    const int tm = w;
    s16x8 ah = *(const s16x8*)&chh[(16 * tm + l15) * 36 + g * 8];
    s16x8 al = *(const s16x8*)&chl[(16 * tm + l15) * 36 + g * 8];
    const int row0 = 16 * tm + 4 * g;
#pragma unroll
    for (int tn = 0; tn < 7; ++tn) {
      s16x8 bh = *(const s16x8*)&chh[(16 * tn + l15) * 36 + g * 8];
      s16x8 bl = *(const s16x8*)&chl[(16 * tn + l15) * 36 + g * 8];
      f32x4 c = mfma16(al, bh, zero4);
      c = mfma16(ah, bl, c);
      c = mfma16(ah, bh, c);
      const int col = 16 * tn + l15;
#pragma unroll
      for (int r = 0; r < 4; ++r) {
        float d = fminf(1.f, fmaxf(-1.f, c[r]));
        cr[tn][r] = d;
        const int row = row0 + r;
        if (row < 100 && col < 100) cgu[row * 100 + col] = f2b(d);
      }
    }
  }
  __syncthreads();

  // ---- P4b: corr regs -> LDS hi/lo (over A/chat/Vt); t0 regs -> LDS hi/lo
  {
    if (w < 7) {
      const int tm = w;
      const int row0 = 16 * tm + 4 * g;
#pragma unroll
      for (int r = 0; r < 4; ++r) {
        const int row = row0 + r;
#pragma unroll
        for (int tn = 0; tn < 7; ++tn) {
          const int col = 16 * tn + l15;
          float d = cr[tn][r];
          u16 hh = f2b(d);
          crh[row * 136 + col] = hh;
          crl[row * 136 + col] = f2b(d - b2f(hh));
        }
        if (l15 < 8) {
          ((u32*)crh)[row * 68 + 56 + l15] = 0;    // cols 112..127 := 0
          ((u32*)crl)[row * 68 + 56 + l15] = 0;
        }
      }
    }
    if (w >= 6) {
      const int j = 16 * (w & 1) + l15;
#pragma unroll
      for (int tm = 0; tm < 7; ++tm) {
#pragma unroll
        for (int r = 0; r < 4; ++r) {
          int m = 16 * tm + 4 * g + r;
          float v = t0r[tm * 4 + r];
          u16 hh = f2b(v);
          t0h[j * 136 + m] = hh;
          t0l[j * 136 + m] = f2b(v - b2f(hh));
        }
      }
      if (g == 0) {
#pragma unroll
        for (int ii = 0; ii < 8; ++ii) ((u32*)t0h)[j * 68 + 56 + ii] = 0;  // m 112..127 := 0
      } else if (g == 1) {
#pragma unroll
        for (int ii = 0; ii < 8; ++ii) ((u32*)t0l)[j * 68 + 56 + ii] = 0;
      }
    }
  }
  __syncthreads();

  // ---- P5: z1 = (corr_hi+corr_lo) @ (t0_hi+t0_lo) + b1 (MFMA) -> HBM + stats
  if (w < 7) {
    const int tm = w;
    float bj0 = b1[l15], bj1 = b1[16 + l15];
    float* zo = z1g + (size_t)b * 3200;
    f32x4 z0 = zero4, z1v = zero4;
#pragma unroll
    for (int kt = 0; kt < 4; ++kt) {
      s16x8 a_h = *(const s16x8*)&crh[(16 * tm + l15) * 136 + kt * 32 + g * 8];
      s16x8 a_l = *(const s16x8*)&crl[(16 * tm + l15) * 136 + kt * 32 + g * 8];
      s16x8 b0h = *(const s16x8*)&t0h[l15 * 136 + kt * 32 + g * 8];
      s16x8 b0l = *(const s16x8*)&t0l[l15 * 136 + kt * 32 + g * 8];
      s16x8 b1h = *(const s16x8*)&t0h[(16 + l15) * 136 + kt * 32 + g * 8];
      s16x8 b1l = *(const s16x8*)&t0l[(16 + l15) * 136 + kt * 32 + g * 8];
      z0 = mfma16(a_l, b0h, z0);  z0 = mfma16(a_h, b0l, z0);  z0 = mfma16(a_h, b0h, z0);
      z1v = mfma16(a_l, b1h, z1v); z1v = mfma16(a_h, b1l, z1v); z1v = mfma16(a_h, b1h, z1v);
    }
    const int row0 = 16 * tm + 4 * g;
#pragma unroll
    for (int r = 0; r < 4; ++r) {
      const int row = row0 + r;
      float v0 = z0[r] + bj0, v1 = z1v[r] + bj1;
      if (row < 100) { zo[row * 32 + l15] = v0; zo[row * 32 + 16 + l15] = v1; }
      float s = v0 + v1, ss = v0 * v0 + v1 * v1;
#pragma unroll
      for (int off = 1; off < 16; off <<= 1) {
        s += __shfl_xor(s, off, 16); ss += __shfl_xor(ss, off, 16);
      }
      if (row < 100 && l15 == 0) { atomicAdd(&stats1[row], s); atomicAdd(&stats1[100 + row], ss); }
    }
  }
}

// ---------------- KB: R2/R7-proven GCN step; corr bf16-in-LDS, unpack in inner loop ----------------
template<int FIN, int FOUT>
__global__ __launch_bounds__(256, 3) void kb_kernel(
    const float* __restrict__ zin,
    const __hip_bfloat16* __restrict__ corr_g,
    const float* __restrict__ W, const float* __restrict__ bias,
    const float* __restrict__ stats_in, float* __restrict__ stats_out,
    float* __restrict__ zout)
{
  constexpr int LOGF  = (FOUT == 16) ? 4 : (FOUT == 8) ? 3 : (FOUT == 4) ? 2 : 1;
  constexpr int LOGFI = (FIN == 32) ? 5 : (FIN == 16) ? 4 : (FIN == 8) ? 3 : 2;
  constexpr int RP = 256 / FOUT;
  constexpr int NR = (100 + RP - 1) / RP;

  __shared__ u32 clLu[100 * 52];                 // corr bf16 pairs, [100][52] u32 (50 used)
  __shared__ float mS[100], vS[100];
  __shared__ float hL[100 * 33];
  __shared__ float tL[100 * (FOUT + 1)];

  const int b = blockIdx.x, tid = threadIdx.x;

  {
    const u32* cgu = (const u32*)(corr_g + (size_t)b * 10000);
    for (int i = tid; i < 5000; i += 256) {
      int n = (i * 5243) >> 18;                  // i/50 for i<5000
      int mm = i - n * 50;
      clLu[n * 52 + mm] = cgu[i];
    }
  }
  if (tid < 100) {
    float cnt  = 8192.0f * (float)FIN;
    float mean = stats_in[tid] / cnt;
    float var  = stats_in[100 + tid] / cnt - mean * mean;
    mS[tid] = mean;
    vS[tid] = rsqrtf(var + 1e-5f);
  }
  __syncthreads();

  {
    const float4* zb4 = (const float4*)(zin + (size_t)b * 100 * FIN);
    for (int i4 = tid; i4 < 25 * FIN; i4 += 256) {
      int n = i4 >> (LOGFI - 2);
      int c = (i4 << 2) & (FIN - 1);
      float4 z = zb4[i4];
      float mn = mS[n], iv = vS[n];
      hL[n * 33 + c + 0] = fast_tanh((z.x - mn) * iv);
      hL[n * 33 + c + 1] = fast_tanh((z.y - mn) * iv);
      hL[n * 33 + c + 2] = fast_tanh((z.z - mn) * iv);
      hL[n * 33 + c + 3] = fast_tanh((z.w - mn) * iv);
    }
  }
  __syncthreads();

  const int j  = tid & (FOUT - 1);
  const int nb = tid >> LOGF;

  {
    float wreg[FIN];
#pragma unroll
    for (int c = 0; c < FIN; ++c) wreg[c] = W[j * FIN + c];
#pragma unroll
    for (int k = 0; k < NR; ++k) {
      int n = nb + k * RP;
      if (n < 100) {
        float a = 0.f;
#pragma unroll
        for (int c = 0; c < FIN; ++c) a = fmaf(hL[n * 33 + c], wreg[c], a);
        tL[n * (FOUT + 1) + j] = a;
      }
    }
  }
  __syncthreads();

  {
    float acc[NR];
    float bj = bias[j];
#pragma unroll
    for (int k = 0; k < NR; ++k) acc[k] = bj;
    int nrow[NR];
#pragma unroll
    for (int k = 0; k < NR; ++k) nrow[k] = min(nb + k * RP, 99);
#pragma unroll 5
    for (int m4 = 0; m4 < 25; ++m4) {
      float ta = tL[(m4 * 4 + 0) * (FOUT + 1) + j];
      float tb = tL[(m4 * 4 + 1) * (FOUT + 1) + j];
      float tc = tL[(m4 * 4 + 2) * (FOUT + 1) + j];
      float td = tL[(m4 * 4 + 3) * (FOUT + 1) + j];
#pragma unroll
      for (int k = 0; k < NR; ++k) {
        u32 p0 = clLu[nrow[k] * 52 + 2 * m4];
        u32 p1 = clLu[nrow[k] * 52 + 2 * m4 + 1];
        acc[k] = fmaf(blo(p0), ta, fmaf(bhi(p0), tb,
                 fmaf(blo(p1), tc, fmaf(bhi(p1), td, acc[k]))));
      }
    }
    float* zo = zout + (size_t)b * 100 * FOUT;
#pragma unroll
    for (int k = 0; k < NR; ++k) {
      int n = nb + k * RP;
      if (n < 100) {
        float v = acc[k];
        zo[n * FOUT + j] = v;
        float s = v, ss = v * v;
#pragma unroll
        for (int off = FOUT >> 1; off; off >>= 1) {
          s  += __shfl_xor(s, off, FOUT);
          ss += __shfl_xor(ss, off, FOUT);
        }
        if (j == 0) {
          atomicAdd(&stats_out[n], s);
          atomicAdd(&stats_out[100 + n], ss);
        }
      }
    }
  }
}

// ---------------- KF: final BN+tanh + [200]->[2] head ----------------
__global__ __launch_bounds__(256) void kf_kernel(
    const float* __restrict__ z5, const float* __restrict__ stats5,
    const float* __restrict__ Wf, const float* __restrict__ bfv,
    float* __restrict__ out)
{
  __shared__ float mS[100], vS[100];
  const int tid = threadIdx.x;
  if (tid < 100) {
    float cnt  = 8192.0f * 2.0f;
    float mean = stats5[tid] / cnt;
    float var  = stats5[100 + tid] / cnt - mean * mean;
    mS[tid] = mean;
    vS[tid] = rsqrtf(var + 1e-5f);
  }
  __syncthreads();
  const int wvid = tid >> 6, lane = tid & 63;
  const int b = blockIdx.x * 4 + wvid;
  const float* zb = z5 + (size_t)b * 200;
  float a0 = 0.f, a1 = 0.f;
#pragma unroll
  for (int p = 0; p < 4; ++p) {
    int jj = lane + p * 64;
    if (jj < 200) {
      int n = jj >> 1;
      float hv = fast_tanh((zb[jj] - mS[n]) * vS[n]);
      a0 = fmaf(hv, Wf[jj], a0);
      a1 = fmaf(hv, Wf[200 + jj], a1);
    }
  }
#pragma unroll
  for (int off = 32; off; off >>= 1) {
    a0 += __shfl_xor(a0, off, 64);
    a1 += __shfl_xor(a1, off, 64);
  }
  if (lane == 0) {
    out[b * 2 + 0] = a0 + bfv[0];
    out[b * 2 + 1] = a1 + bfv[1];
  }
}

extern "C" void kernel_launch(void* const* d_in, const int* in_sizes, int n_in,
                              void* d_out, int out_size, void* d_ws, size_t ws_size,
                              hipStream_t stream)
{
  const float* x  = (const float*)d_in[0];
  const float* Wq = (const float*)d_in[1];
  const float* bq = (const float*)d_in[2];
  const float* Wk = (const float*)d_in[3];
  const float* bk = (const float*)d_in[4];
  const float* Wv = (const float*)d_in[5];
  const float* bv = (const float*)d_in[6];
  const float* W1 = (const float*)d_in[7];
  const float* b1 = (const float*)d_in[8];
  const float* W2 = (const float*)d_in[9];
  const float* b2 = (const float*)d_in[10];
  const float* W3 = (const float*)d_in[11];
  const float* b3 = (const float*)d_in[12];
  const float* W4 = (const float*)d_in[13];
  const float* b4 = (const float*)d_in[14];
  const float* W5 = (const float*)d_in[15];
  const float* b5 = (const float*)d_in[16];
  const float* Wf = (const float*)d_in[17];
  const float* bf = (const float*)d_in[18];
  float* out = (float*)d_out;

  char* ws = (char*)d_ws;
  // ws: corr bf16 [8192,100,100] @0 ; zA f32 [8192,100,32] @163840000 ;
  //     zB f32 [8192,100,16] @268697600 ; stats 5*[200] f32 @321126400
  const size_t NEED = 321130400ull;
  if (ws_size < NEED) return;

  __hip_bfloat16* corr_g = (__hip_bfloat16*)ws;
  float* zA    = (float*)(ws + 163840000ull);
  float* zB    = (float*)(ws + 268697600ull);
  float* stats = (float*)(ws + 321126400ull);

  (void)hipMemsetAsync(stats, 0, 5 * 200 * sizeof(float), stream);

  ka_kernel<<<8192, 512, 0, stream>>>(x, Wq, bq, Wk, bk, Wv, bv, W1, b1,
                                      corr_g, zA, stats);
  kb_kernel<32, 16><<<8192, 256, 0, stream>>>(zA, corr_g, W2, b2, stats,       stats + 200, zB);
  kb_kernel<16,  8><<<8192, 256, 0, stream>>>(zB, corr_g, W3, b3, stats + 200, stats + 400, zA);
  kb_kernel< 8,  4><<<8192, 256, 0, stream>>>(zA, corr_g, W4, b4, stats + 400, stats + 600, zB);
  kb_kernel< 4,  2><<<8192, 256, 0, stream>>>(zB, corr_g, W5, b5, stats + 600, stats + 800, zA);
  kf_kernel<<<2048, 256, 0, stream>>>(zA, stats + 800, Wf, bf, out);
}